// Round 11
// baseline (261.070 us; speedup 1.0000x reference)
//
#include <hip/hip_runtime.h>
#include <float.h>
#include <math.h>

#define BATCH 8
#define NPTS 4096
#define KNN 10
#define BN (BATCH * NPTS)          // 32768 points per cloud
#define TPB 512                    // 8 waves
#define WAVES 8                    // scan segments, one per wave (wave-uniform LDS reads)
#define QPB 64                     // queries per block (1 per lane)
#define HALFPTS 2048               // points staged per pass (32 KiB as float4)
#define SEGC (HALFPTS / WAVES)     // 256 candidates per wave per pass
#define GRIDX (NPTS / QPB)         // 64 -> grid 64x8x2 = 1024 blocks = 4/CU
#define TOTAL_BLOCKS (GRIDX * BATCH * 2)
#define KB_STRIDE 11               // merge keybuf row stride (odd)

__device__ inline float med3f(float x, float a, float b) {
    return __builtin_amdgcn_fmed3f(x, a, b);
}

// branchless sorted insert of key into ascending k[0..9] (drop largest)
#define INSERT(karr, key)                                              \
    do {                                                               \
        _Pragma("unroll")                                              \
        for (int _j = KNN - 1; _j >= 1; --_j)                          \
            karr[_j] = med3f((key), karr[_j - 1], karr[_j]);           \
        karr[0] = fminf((key), karr[0]);                               \
    } while (0)

// distance + pack + insert for one candidate float4 _p at index _gi (Q=1)
#define PROC(_p, _gi)                                                  \
    do {                                                               \
        float _d = fmaf((_p).z, a0z, fmaf((_p).y, a0y, fmaf((_p).x, a0x, (_p).w))); \
        float _k = __uint_as_float((__float_as_uint(_d) & 0xFFFFF000u) | (_gi)); \
        INSERT(k, _k);                                                 \
    } while (0)

#define PROC4(P, _gi)                                                  \
    do {                                                               \
        PROC(P##0, (_gi) + 0);                                         \
        PROC(P##1, (_gi) + 1);                                         \
        PROC(P##2, (_gi) + 2);                                         \
        PROC(P##3, (_gi) + 3);                                         \
    } while (0)

#define LOAD4(P, _off)                                                 \
    do {                                                               \
        P##0 = pts[(_off) + 0]; P##1 = pts[(_off) + 1];                \
        P##2 = pts[(_off) + 2]; P##3 = pts[(_off) + 3];                \
    } while (0)

// Eigenvector of smallest eigenvalue of symmetric 3x3
__device__ inline void smallest_eigvec(float a00, float a01, float a02,
                                       float a11, float a12, float a22,
                                       float& vx, float& vy, float& vz) {
    float p1 = a01 * a01 + a02 * a02 + a12 * a12;
    float q = (a00 + a11 + a22) * (1.0f / 3.0f);
    float b00 = a00 - q, b11 = a11 - q, b22 = a22 - q;
    float p2 = b00 * b00 + b11 * b11 + b22 * b22 + 2.0f * p1;
    float p = sqrtf(p2 * (1.0f / 6.0f));
    if (p < 1e-20f) { vx = 1.0f; vy = 0.0f; vz = 0.0f; return; }
    float ip = 1.0f / p;
    float c00 = b00 * ip, c01 = a01 * ip, c02 = a02 * ip;
    float c11 = b11 * ip, c12 = a12 * ip, c22 = b22 * ip;
    float detB = c00 * (c11 * c22 - c12 * c12)
               - c01 * (c01 * c22 - c12 * c02)
               + c02 * (c01 * c12 - c11 * c02);
    float r = 0.5f * detB;
    r = fminf(1.0f, fmaxf(-1.0f, r));
    float phi = acosf(r) * (1.0f / 3.0f);
    float lmin = q + 2.0f * p * cosf(phi + 2.0943951023931953f);

    float m00 = a00 - lmin, m11 = a11 - lmin, m22 = a22 - lmin;
    float r0x = m00, r0y = a01, r0z = a02;
    float r1x = a01, r1y = m11, r1z = a12;
    float r2x = a02, r2y = a12, r2z = m22;
    float c0x = r0y * r1z - r0z * r1y, c0y = r0z * r1x - r0x * r1z, c0z = r0x * r1y - r0y * r1x;
    float c1x = r0y * r2z - r0z * r2y, c1y = r0z * r2x - r0x * r2z, c1z = r0x * r2y - r0y * r2x;
    float c2x = r1y * r2z - r1z * r2y, c2y = r1z * r2x - r1x * r2z, c2z = r1x * r2y - r1y * r2x;
    float n0 = c0x * c0x + c0y * c0y + c0z * c0z;
    float n1 = c1x * c1x + c1y * c1y + c1z * c1z;
    float n2 = c2x * c2x + c2y * c2y + c2z * c2z;
    float bx = c0x, by = c0y, bz = c0z, bnm = n0;
    if (n1 > bnm) { bx = c1x; by = c1y; bz = c1z; bnm = n1; }
    if (n2 > bnm) { bx = c2x; by = c2y; bz = c2z; bnm = n2; }
    if (bnm < 1e-30f) { vx = 1.0f; vy = 0.0f; vz = 0.0f; return; }
    float inv = rsqrtf(bnm);
    vx = bx * inv; vy = by * inv; vz = bz * inv;
}

__global__ void init_counter_kernel(unsigned* __restrict__ counter) {
    if (threadIdx.x == 0) *counter = 0u;
}

// One block = 64 points of one (batch, cloud). 8 waves; lane l owns query
// base+l; wave w scans segment w (wave-uniform broadcast LDS reads) with a
// 4+4 register double-buffer fenced by sched_barrier. launch_bounds(512,2):
// r9 showed the allocator behaves (VGPR~64) under min-waves=2; at VGPR<=64
// the HW still co-schedules 4 blocks/CU (LDS 35KiB -> 4 resident) = 8
// waves/SIMD. Last-finishing block computes the loss from planar nbuf.
__global__ __launch_bounds__(TPB, 2) void knn_normal_loss(
    const float* __restrict__ pred, const float* __restrict__ gt,
    float* __restrict__ nbuf /* [2][3][BN] planar */,
    unsigned* __restrict__ counter, float* __restrict__ out) {
    __shared__ float4 pts[HALFPTS + 8];   // +8: prefetch over-read pad
    __shared__ float red[TPB];
    __shared__ int islast;

    const int b = blockIdx.y;
    const int cloud = blockIdx.z;
    const float* __restrict__ base = (cloud == 0 ? pred : gt) + b * 3 * NPTS;
    const int tid = threadIdx.x;
    const int lane = tid & 63;
    const int w = tid >> 6;           // wave id = segment id
    const int s0 = w * SEGC;          // wave-uniform segment offset
    float* keybuf = (float*)pts;

    const int pt = blockIdx.x * QPB + lane;
    const float a0x = -2.0f * base[pt];
    const float a0y = -2.0f * base[NPTS + pt];
    const float a0z = -2.0f * base[2 * NPTS + pt];

    float k[KNN];
#pragma unroll
    for (int j = 0; j < KNN; ++j) k[j] = FLT_MAX;

    for (int pass = 0; pass < 2; ++pass) {
        const int pb = pass * HALFPTS;
        for (int i = tid; i < HALFPTS; i += TPB) {
            float x = base[pb + i];
            float y = base[NPTS + pb + i];
            float z = base[2 * NPTS + pb + i];
            pts[i] = make_float4(x, y, z, fmaf(x, x, fmaf(y, y, z * z)));
        }
        __syncthreads();

        const unsigned gb = (unsigned)(pb + s0);
        float4 A0, A1, A2, A3, B0, B1, B2, B3;
        LOAD4(A, s0);
        __builtin_amdgcn_sched_barrier(0);
        for (int c = 0; c < SEGC; c += 8) {
            LOAD4(B, s0 + c + 4);
            __builtin_amdgcn_sched_barrier(0);
            PROC4(A, gb + (unsigned)c);
            __builtin_amdgcn_sched_barrier(0);
            LOAD4(A, s0 + c + 8);     // last iter reads pad (discarded)
            __builtin_amdgcn_sched_barrier(0);
            PROC4(B, gb + (unsigned)c + 4u);
            __builtin_amdgcn_sched_barrier(0);
        }
        __syncthreads();              // scan done before restage / keybuf aliasing
    }

    // tree merge 8 -> 4 -> 2 -> 1 (keybuf aliases dead stage buffer)
    for (int half = WAVES / 2; half >= 1; half >>= 1) {
        if (w >= half && w < 2 * half) {
            float* dst = keybuf + ((w - half) * 64 + lane) * KB_STRIDE;
#pragma unroll
            for (int j = 0; j < KNN; ++j) dst[j] = k[j];
        }
        __syncthreads();
        if (w < half) {
            const float* src = keybuf + (w * 64 + lane) * KB_STRIDE;
#pragma unroll
            for (int j = 0; j < KNN; ++j) {
                float sk = src[j];
                INSERT(k, sk);
            }
        }
        __syncthreads();
    }

    if (w == 0) {
        // raw-moment covariance of the 10 neighbors
        float sx = 0.f, sy = 0.f, sz = 0.f;
        float sxx = 0.f, sxy = 0.f, sxz = 0.f, syy = 0.f, syz = 0.f, szz = 0.f;
#pragma unroll
        for (int j = 0; j < KNN; ++j) {
            int idx = (int)(__float_as_uint(k[j]) & 0xFFFu);
            float x = base[idx], y = base[NPTS + idx], z = base[2 * NPTS + idx];
            sx += x; sy += y; sz += z;
            sxx = fmaf(x, x, sxx); sxy = fmaf(x, y, sxy); sxz = fmaf(x, z, sxz);
            syy = fmaf(y, y, syy); syz = fmaf(y, z, syz); szz = fmaf(z, z, szz);
        }
        const float iK = 1.0f / KNN;
        float mx = sx * iK, my = sy * iK, mz = sz * iK;
        float vx, vy, vz;
        smallest_eigvec(sxx * iK - mx * mx, sxy * iK - mx * my, sxz * iK - mx * mz,
                        syy * iK - my * my, syz * iK - my * mz, szz * iK - mz * mz,
                        vx, vy, vz);

        float* np = nbuf + cloud * 3 * BN;
        const int oidx = b * NPTS + pt;
        np[oidx] = vx;
        np[BN + oidx] = vy;
        np[2 * BN + oidx] = vz;
    }

    // completion protocol: publish nbuf, last block computes the loss
    __threadfence();
    __syncthreads();
    if (tid == 0) {
        unsigned old = atomicAdd(counter, 1u);
        islast = (old == TOTAL_BLOCKS - 1) ? 1 : 0;
    }
    __syncthreads();

    if (islast) {
        __threadfence();   // acquire: order reads after counter observation
        const float* pn = nbuf;
        const float* gn = nbuf + 3 * BN;
        float acc = 0.f;
        for (int i = tid; i < BN; i += TPB) {
            float px = pn[i], py = pn[BN + i], pz = pn[2 * BN + i];
            float gx = gn[i], gy = gn[BN + i], gz = gn[2 * BN + i];
            float dot = px * gx + py * gy + pz * gz;
            float npn = sqrtf(px * px + py * py + pz * pz);
            float ngn = sqrtf(gx * gx + gy * gy + gz * gz);
            float denom = fmaxf(npn * ngn, 1e-8f);
            acc += 1.0f - fabsf(dot / denom);
        }
        red[tid] = acc;
        __syncthreads();
        for (int s = TPB / 2; s > 0; s >>= 1) {
            if (tid < s) red[tid] += red[tid + s];
            __syncthreads();
        }
        if (tid == 0) out[0] = red[0] * (1.0f / BN);
    }
}

extern "C" void kernel_launch(void* const* d_in, const int* in_sizes, int n_in,
                              void* d_out, int out_size, void* d_ws, size_t ws_size,
                              hipStream_t stream) {
    const float* pred = (const float*)d_in[0];
    const float* gt = (const float*)d_in[1];
    float* out = (float*)d_out;
    unsigned* counter = (unsigned*)d_ws;     // first 64 B slot
    float* nbuf = (float*)d_ws + 16;         // 6*BN floats = 768 KiB

    init_counter_kernel<<<1, 64, 0, stream>>>(counter);
    dim3 grid(GRIDX, BATCH, 2);              // 64 x 8 x 2 = 1024 blocks
    knn_normal_loss<<<grid, TPB, 0, stream>>>(pred, gt, nbuf, counter, out);
}

// Round 12
// 186.256 us; speedup vs baseline: 1.4017x; 1.4017x over previous
//
#include <hip/hip_runtime.h>
#include <float.h>
#include <math.h>

#define BATCH 8
#define NPTS 4096
#define KNN 10
#define BN (BATCH * NPTS)          // 32768 points per cloud
#define TPB 512                    // 8 waves
#define WAVES 8                    // scan segments, one per wave (wave-uniform LDS reads)
#define QPB 64                     // queries per block (1 per lane)
#define HALFPTS 2048               // points staged per pass (32 KiB as float4)
#define SEGC (HALFPTS / WAVES)     // 256 candidates per wave per pass
#define GRIDX (NPTS / QPB)         // 64 -> grid 64x8 = 512 blocks = 2/CU
#define KB_STRIDE 11               // merge keybuf row stride (odd -> conflict-light)

__device__ inline float med3f(float x, float a, float b) {
    return __builtin_amdgcn_fmed3f(x, a, b);
}

// branchless sorted insert of key into ascending k[0..9] (drop largest);
// all 9 med3 read pre-insert values -> mutually independent
#define INSERT(karr, key)                                              \
    do {                                                               \
        _Pragma("unroll")                                              \
        for (int _j = KNN - 1; _j >= 1; --_j)                          \
            karr[_j] = med3f((key), karr[_j - 1], karr[_j]);           \
        karr[0] = fminf((key), karr[0]);                               \
    } while (0)

// one candidate: dist + pack + GUARDED insert. The guard compiles to a
// vcc compare + s_cbranch_execz: when no lane of the wave passes (59% of
// candidates late in the scan), the 10-op insert chain is skipped entirely.
#define CAND(_p, _gi, karr)                                            \
    do {                                                               \
        float _d = fmaf((_p).z, a0z, fmaf((_p).y, a0y, fmaf((_p).x, a0x, (_p).w))); \
        float _k = __uint_as_float((__float_as_uint(_d) & 0xFFFFF000u) | (_gi)); \
        if (_k < karr[KNN - 1]) { INSERT(karr, _k); }                  \
    } while (0)

// Eigenvector of smallest eigenvalue of symmetric 3x3
__device__ inline void smallest_eigvec(float a00, float a01, float a02,
                                       float a11, float a12, float a22,
                                       float& vx, float& vy, float& vz) {
    float p1 = a01 * a01 + a02 * a02 + a12 * a12;
    float q = (a00 + a11 + a22) * (1.0f / 3.0f);
    float b00 = a00 - q, b11 = a11 - q, b22 = a22 - q;
    float p2 = b00 * b00 + b11 * b11 + b22 * b22 + 2.0f * p1;
    float p = sqrtf(p2 * (1.0f / 6.0f));
    if (p < 1e-20f) { vx = 1.0f; vy = 0.0f; vz = 0.0f; return; }
    float ip = 1.0f / p;
    float c00 = b00 * ip, c01 = a01 * ip, c02 = a02 * ip;
    float c11 = b11 * ip, c12 = a12 * ip, c22 = b22 * ip;
    float detB = c00 * (c11 * c22 - c12 * c12)
               - c01 * (c01 * c22 - c12 * c02)
               + c02 * (c01 * c12 - c11 * c02);
    float r = 0.5f * detB;
    r = fminf(1.0f, fmaxf(-1.0f, r));
    float phi = acosf(r) * (1.0f / 3.0f);
    float lmin = q + 2.0f * p * cosf(phi + 2.0943951023931953f);

    float m00 = a00 - lmin, m11 = a11 - lmin, m22 = a22 - lmin;
    float r0x = m00, r0y = a01, r0z = a02;
    float r1x = a01, r1y = m11, r1z = a12;
    float r2x = a02, r2y = a12, r2z = m22;
    float c0x = r0y * r1z - r0z * r1y, c0y = r0z * r1x - r0x * r1z, c0z = r0x * r1y - r0y * r1x;
    float c1x = r0y * r2z - r0z * r2y, c1y = r0z * r2x - r0x * r2z, c1z = r0x * r2y - r0y * r2x;
    float c2x = r1y * r2z - r1z * r2y, c2y = r1z * r2x - r1x * r2z, c2z = r1x * r2y - r1y * r2x;
    float n0 = c0x * c0x + c0y * c0y + c0z * c0z;
    float n1 = c1x * c1x + c1y * c1y + c1z * c1z;
    float n2 = c2x * c2x + c2y * c2y + c2z * c2z;
    float bx = c0x, by = c0y, bz = c0z, bnm = n0;
    if (n1 > bnm) { bx = c1x; by = c1y; bz = c1z; bnm = n1; }
    if (n2 > bnm) { bx = c2x; by = c2y; bz = c2z; bnm = n2; }
    if (bnm < 1e-30f) { vx = 1.0f; vy = 0.0f; vz = 0.0f; return; }
    float inv = rsqrtf(bnm);
    vx = bx * inv; vy = by * inv; vz = bz * inv;
}

// full kNN of query pt over cloud `basep` -> (after tree merge) wave 0 holds
// the final sorted top-10 in karr. 8-candidate unconditional load groups keep
// ds_read_b128 batched ahead of the per-candidate guarded inserts.
#define SCAN_CLOUD(basep, karr)                                        \
    do {                                                               \
        _Pragma("unroll")                                              \
        for (int _j = 0; _j < KNN; ++_j) karr[_j] = FLT_MAX;           \
        const float a0x = -2.0f * (basep)[pt];                         \
        const float a0y = -2.0f * (basep)[NPTS + pt];                  \
        const float a0z = -2.0f * (basep)[2 * NPTS + pt];              \
        for (int _pass = 0; _pass < 2; ++_pass) {                      \
            const int _pb = _pass * HALFPTS;                           \
            for (int _i = tid; _i < HALFPTS; _i += TPB) {              \
                float _x = (basep)[_pb + _i];                          \
                float _y = (basep)[NPTS + _pb + _i];                   \
                float _z = (basep)[2 * NPTS + _pb + _i];               \
                pts[_i] = make_float4(_x, _y, _z, fmaf(_x, _x, fmaf(_y, _y, _z * _z))); \
            }                                                          \
            __syncthreads();                                           \
            const unsigned _gb = (unsigned)(_pb + s0);                 \
            for (int _c = 0; _c < SEGC; _c += 8) {                     \
                float4 _p0 = pts[s0 + _c + 0];                         \
                float4 _p1 = pts[s0 + _c + 1];                         \
                float4 _p2 = pts[s0 + _c + 2];                         \
                float4 _p3 = pts[s0 + _c + 3];                         \
                float4 _p4 = pts[s0 + _c + 4];                         \
                float4 _p5 = pts[s0 + _c + 5];                         \
                float4 _p6 = pts[s0 + _c + 6];                         \
                float4 _p7 = pts[s0 + _c + 7];                         \
                unsigned _gi = _gb + (unsigned)_c;                     \
                CAND(_p0, _gi + 0, karr);                              \
                CAND(_p1, _gi + 1, karr);                              \
                CAND(_p2, _gi + 2, karr);                              \
                CAND(_p3, _gi + 3, karr);                              \
                CAND(_p4, _gi + 4, karr);                              \
                CAND(_p5, _gi + 5, karr);                              \
                CAND(_p6, _gi + 6, karr);                              \
                CAND(_p7, _gi + 7, karr);                              \
            }                                                          \
            __syncthreads();                                           \
        }                                                              \
        /* tree merge 8->4->2->1; keybuf aliases dead stage buffer */  \
        for (int _half = WAVES / 2; _half >= 1; _half >>= 1) {         \
            if (w >= _half && w < 2 * _half) {                         \
                float* _dst = keybuf + ((w - _half) * 64 + lane) * KB_STRIDE; \
                _Pragma("unroll")                                      \
                for (int _j = 0; _j < KNN; ++_j) _dst[_j] = karr[_j];  \
            }                                                          \
            __syncthreads();                                           \
            if (w < _half) {                                           \
                const float* _src = keybuf + (w * 64 + lane) * KB_STRIDE; \
                _Pragma("unroll")                                      \
                for (int _j = 0; _j < KNN; ++_j) {                     \
                    float _sk = _src[_j];                              \
                    INSERT(karr, _sk);                                 \
                }                                                      \
            }                                                          \
            __syncthreads();                                           \
        }                                                              \
    } while (0)

// covariance of the 10 neighbors (indices in karr low 12 bits) + eigenvector
#define COMPUTE_NORMAL(karr, basep, vx, vy, vz)                        \
    do {                                                               \
        float _sx = 0.f, _sy = 0.f, _sz = 0.f;                         \
        float _sxx = 0.f, _sxy = 0.f, _sxz = 0.f;                      \
        float _syy = 0.f, _syz = 0.f, _szz = 0.f;                      \
        _Pragma("unroll")                                              \
        for (int _j = 0; _j < KNN; ++_j) {                             \
            int _idx = (int)(__float_as_uint(karr[_j]) & 0xFFFu);      \
            float _x = (basep)[_idx];                                  \
            float _y = (basep)[NPTS + _idx];                           \
            float _z = (basep)[2 * NPTS + _idx];                       \
            _sx += _x; _sy += _y; _sz += _z;                           \
            _sxx = fmaf(_x, _x, _sxx); _sxy = fmaf(_x, _y, _sxy); _sxz = fmaf(_x, _z, _sxz); \
            _syy = fmaf(_y, _y, _syy); _syz = fmaf(_y, _z, _syz); _szz = fmaf(_z, _z, _szz); \
        }                                                              \
        const float _iK = 1.0f / KNN;                                  \
        float _mx = _sx * _iK, _my = _sy * _iK, _mz = _sz * _iK;       \
        smallest_eigvec(_sxx * _iK - _mx * _mx, _sxy * _iK - _mx * _my, \
                        _sxz * _iK - _mx * _mz, _syy * _iK - _my * _my, \
                        _syz * _iK - _my * _mz, _szz * _iK - _mz * _mz, \
                        vx, vy, vz);                                   \
    } while (0)

__global__ void zero_out_kernel(float* __restrict__ out) {
    if (threadIdx.x == 0) out[0] = 0.0f;
}

// One block = 64 points of one batch, BOTH clouds. 8 waves; lane l owns
// point base+l; wave w scans segment w (wave-uniform broadcast LDS reads).
// Guarded inserts skip the med3 chain when no lane improves its top-10.
// Loss computed in-block by wave 0, one atomicAdd per block.
__global__ __launch_bounds__(TPB, 2) void knn_normal_loss(
    const float* __restrict__ pred, const float* __restrict__ gt,
    float* __restrict__ out) {
    __shared__ float4 pts[HALFPTS];   // 32 KiB; aliased as merge keybuf

    const int b = blockIdx.y;
    const float* __restrict__ baseP = pred + b * 3 * NPTS;
    const float* __restrict__ baseG = gt + b * 3 * NPTS;
    const int tid = threadIdx.x;
    const int lane = tid & 63;
    const int w = tid >> 6;           // wave id = segment id
    const int s0 = w * SEGC;          // wave-uniform segment offset
    float* keybuf = (float*)pts;

    const int pt = blockIdx.x * QPB + lane;

    float kP[KNN], kG[KNN];

    SCAN_CLOUD(baseP, kP);            // pred: scan + merge (wave 0 holds result)
    SCAN_CLOUD(baseG, kG);            // gt:   scan + merge

    if (w == 0) {
        float pvx, pvy, pvz, gvx, gvy, gvz;
        COMPUTE_NORMAL(kP, baseP, pvx, pvy, pvz);
        COMPUTE_NORMAL(kG, baseG, gvx, gvy, gvz);
        float dot = pvx * gvx + pvy * gvy + pvz * gvz;
        float npn = sqrtf(pvx * pvx + pvy * pvy + pvz * pvz);
        float ngn = sqrtf(gvx * gvx + gvy * gvy + gvz * gvz);
        float acc = 1.0f - fabsf(dot / fmaxf(npn * ngn, 1e-8f));
        // wave reduction, then one atomic per block
        for (int off = 32; off > 0; off >>= 1) acc += __shfl_down(acc, off);
        if (lane == 0) atomicAdd(out, acc * (1.0f / (float)BN));
    }
}

extern "C" void kernel_launch(void* const* d_in, const int* in_sizes, int n_in,
                              void* d_out, int out_size, void* d_ws, size_t ws_size,
                              hipStream_t stream) {
    const float* pred = (const float*)d_in[0];
    const float* gt = (const float*)d_in[1];
    float* out = (float*)d_out;

    zero_out_kernel<<<1, 64, 0, stream>>>(out);
    dim3 grid(GRIDX, BATCH);          // 64 x 8 = 512 blocks (2 per CU)
    knn_normal_loss<<<grid, TPB, 0, stream>>>(pred, gt, out);
}

// Round 13
// 172.507 us; speedup vs baseline: 1.5134x; 1.0797x over previous
//
#include <hip/hip_runtime.h>
#include <float.h>
#include <math.h>

#define BATCH 8
#define NPTS 4096
#define KNN 10
#define BN (BATCH * NPTS)          // 32768 points per cloud
#define TPB 1024                   // 16 waves
#define WAVES 16                   // scan segments, one per wave (wave-uniform LDS reads)
#define QPB 128                    // queries per block = 64 lanes x Q=2
#define SEGC (NPTS / WAVES)        // 256 candidates per wave (single full-cloud stage)
#define GRIDX (NPTS / QPB)         // 32 -> grid 32x8 = 256 blocks = 1/CU, 16 waves/CU
#define KB_STRIDE (2 * KNN + 1)    // 21: merge keybuf row stride (odd -> 2-way banks, free)

__device__ inline float med3f(float x, float a, float b) {
    return __builtin_amdgcn_fmed3f(x, a, b);
}

// branchless sorted insert of key into ascending k[0..9] (drop largest);
// all 9 med3 read pre-insert values -> mutually independent
#define INSERT(karr, key)                                              \
    do {                                                               \
        _Pragma("unroll")                                              \
        for (int _j = KNN - 1; _j >= 1; --_j)                          \
            karr[_j] = med3f((key), karr[_j - 1], karr[_j]);           \
        karr[0] = fminf((key), karr[0]);                               \
    } while (0)

// distance + pack + two inserts for one candidate float4 _p at index _gi
#define PROC(_p, _gi, ka, kb)                                          \
    do {                                                               \
        float _d0 = fmaf((_p).z, a0z, fmaf((_p).y, a0y, fmaf((_p).x, a0x, (_p).w))); \
        float _d1 = fmaf((_p).z, a1z, fmaf((_p).y, a1y, fmaf((_p).x, a1x, (_p).w))); \
        float _k0 = __uint_as_float((__float_as_uint(_d0) & 0xFFFFF000u) | (_gi)); \
        float _k1 = __uint_as_float((__float_as_uint(_d1) & 0xFFFFF000u) | (_gi)); \
        INSERT(ka, _k0);                                               \
        INSERT(kb, _k1);                                               \
    } while (0)

#define PROC8(P, _gi, ka, kb)                                          \
    do {                                                               \
        PROC(P##0, (_gi) + 0, ka, kb);                                 \
        PROC(P##1, (_gi) + 1, ka, kb);                                 \
        PROC(P##2, (_gi) + 2, ka, kb);                                 \
        PROC(P##3, (_gi) + 3, ka, kb);                                 \
        PROC(P##4, (_gi) + 4, ka, kb);                                 \
        PROC(P##5, (_gi) + 5, ka, kb);                                 \
        PROC(P##6, (_gi) + 6, ka, kb);                                 \
        PROC(P##7, (_gi) + 7, ka, kb);                                 \
    } while (0)

#define LOAD8(P, _off)                                                 \
    do {                                                               \
        P##0 = pts[(_off) + 0]; P##1 = pts[(_off) + 1];                \
        P##2 = pts[(_off) + 2]; P##3 = pts[(_off) + 3];                \
        P##4 = pts[(_off) + 4]; P##5 = pts[(_off) + 5];                \
        P##6 = pts[(_off) + 6]; P##7 = pts[(_off) + 7];                \
    } while (0)

// Eigenvector of smallest eigenvalue of symmetric 3x3
__device__ inline void smallest_eigvec(float a00, float a01, float a02,
                                       float a11, float a12, float a22,
                                       float& vx, float& vy, float& vz) {
    float p1 = a01 * a01 + a02 * a02 + a12 * a12;
    float q = (a00 + a11 + a22) * (1.0f / 3.0f);
    float b00 = a00 - q, b11 = a11 - q, b22 = a22 - q;
    float p2 = b00 * b00 + b11 * b11 + b22 * b22 + 2.0f * p1;
    float p = sqrtf(p2 * (1.0f / 6.0f));
    if (p < 1e-20f) { vx = 1.0f; vy = 0.0f; vz = 0.0f; return; }
    float ip = 1.0f / p;
    float c00 = b00 * ip, c01 = a01 * ip, c02 = a02 * ip;
    float c11 = b11 * ip, c12 = a12 * ip, c22 = b22 * ip;
    float detB = c00 * (c11 * c22 - c12 * c12)
               - c01 * (c01 * c22 - c12 * c02)
               + c02 * (c01 * c12 - c11 * c02);
    float r = 0.5f * detB;
    r = fminf(1.0f, fmaxf(-1.0f, r));
    float phi = acosf(r) * (1.0f / 3.0f);
    float lmin = q + 2.0f * p * cosf(phi + 2.0943951023931953f);

    float m00 = a00 - lmin, m11 = a11 - lmin, m22 = a22 - lmin;
    float r0x = m00, r0y = a01, r0z = a02;
    float r1x = a01, r1y = m11, r1z = a12;
    float r2x = a02, r2y = a12, r2z = m22;
    float c0x = r0y * r1z - r0z * r1y, c0y = r0z * r1x - r0x * r1z, c0z = r0x * r1y - r0y * r1x;
    float c1x = r0y * r2z - r0z * r2y, c1y = r0z * r2x - r0x * r2z, c1z = r0x * r2y - r0y * r2x;
    float c2x = r1y * r2z - r1z * r2y, c2y = r1z * r2x - r1x * r2z, c2z = r1x * r2y - r1y * r2x;
    float n0 = c0x * c0x + c0y * c0y + c0z * c0z;
    float n1 = c1x * c1x + c1y * c1y + c1z * c1z;
    float n2 = c2x * c2x + c2y * c2y + c2z * c2z;
    float bx = c0x, by = c0y, bz = c0z, bnm = n0;
    if (n1 > bnm) { bx = c1x; by = c1y; bz = c1z; bnm = n1; }
    if (n2 > bnm) { bx = c2x; by = c2y; bz = c2z; bnm = n2; }
    if (bnm < 1e-30f) { vx = 1.0f; vy = 0.0f; vz = 0.0f; return; }
    float inv = rsqrtf(bnm);
    vx = bx * inv; vy = by * inv; vz = bz * inv;
}

// full kNN of queries (pt0, pt1) over cloud `basep`; wave 0 ends with the
// final top-10s in ka/kb. Single full-cloud LDS stage (64 KiB); register
// double-buffer (8+8 float4) fenced by sched_barrier keeps 8 ds_read_b128
// in flight behind ~960 cyc of independent insert VALU.
#define SCAN_CLOUD(basep, ka, kb)                                      \
    do {                                                               \
        _Pragma("unroll")                                              \
        for (int _j = 0; _j < KNN; ++_j) { ka[_j] = FLT_MAX; kb[_j] = FLT_MAX; } \
        const float a0x = -2.0f * (basep)[pt0];                        \
        const float a0y = -2.0f * (basep)[NPTS + pt0];                 \
        const float a0z = -2.0f * (basep)[2 * NPTS + pt0];             \
        const float a1x = -2.0f * (basep)[pt1];                        \
        const float a1y = -2.0f * (basep)[NPTS + pt1];                 \
        const float a1z = -2.0f * (basep)[2 * NPTS + pt1];             \
        for (int _i = tid; _i < NPTS; _i += TPB) {                     \
            float _x = (basep)[_i];                                    \
            float _y = (basep)[NPTS + _i];                             \
            float _z = (basep)[2 * NPTS + _i];                         \
            pts[_i] = make_float4(_x, _y, _z, fmaf(_x, _x, fmaf(_y, _y, _z * _z))); \
        }                                                              \
        __syncthreads();                                               \
        {                                                              \
            const unsigned _gb = (unsigned)s0;                         \
            float4 A0, A1, A2, A3, A4, A5, A6, A7;                     \
            float4 B0, B1, B2, B3, B4, B5, B6, B7;                     \
            LOAD8(A, s0);                                              \
            __builtin_amdgcn_sched_barrier(0);                         \
            for (int _c = 0; _c < SEGC; _c += 16) {                    \
                LOAD8(B, s0 + _c + 8);                                 \
                __builtin_amdgcn_sched_barrier(0);                     \
                PROC8(A, _gb + (unsigned)_c, ka, kb);                  \
                __builtin_amdgcn_sched_barrier(0);                     \
                LOAD8(A, s0 + _c + 16);  /* last iter reads pad */     \
                __builtin_amdgcn_sched_barrier(0);                     \
                PROC8(B, _gb + (unsigned)_c + 8u, ka, kb);             \
                __builtin_amdgcn_sched_barrier(0);                     \
            }                                                          \
        }                                                              \
        __syncthreads();   /* scan done before keybuf aliasing */      \
        /* tree merge 16->8->4->2->1; keybuf aliases dead stage */     \
        for (int _half = WAVES / 2; _half >= 1; _half >>= 1) {         \
            if (w >= _half && w < 2 * _half) {                         \
                float* _dst = keybuf + ((w - _half) * 64 + lane) * KB_STRIDE; \
                _Pragma("unroll")                                      \
                for (int _j = 0; _j < KNN; ++_j) { _dst[_j] = ka[_j]; _dst[KNN + _j] = kb[_j]; } \
            }                                                          \
            __syncthreads();                                           \
            if (w < _half) {                                           \
                const float* _src = keybuf + (w * 64 + lane) * KB_STRIDE; \
                _Pragma("unroll")                                      \
                for (int _j = 0; _j < KNN; ++_j) {                     \
                    float _sa = _src[_j], _sb = _src[KNN + _j];        \
                    INSERT(ka, _sa);                                   \
                    INSERT(kb, _sb);                                   \
                }                                                      \
            }                                                          \
            __syncthreads();                                           \
        }                                                              \
    } while (0)

// covariance of the 10 neighbors (indices in karr low 12 bits) + eigenvector
#define COMPUTE_NORMAL(karr, basep, vx, vy, vz)                        \
    do {                                                               \
        float _sx = 0.f, _sy = 0.f, _sz = 0.f;                         \
        float _sxx = 0.f, _sxy = 0.f, _sxz = 0.f;                      \
        float _syy = 0.f, _syz = 0.f, _szz = 0.f;                      \
        _Pragma("unroll")                                              \
        for (int _j = 0; _j < KNN; ++_j) {                             \
            int _idx = (int)(__float_as_uint(karr[_j]) & 0xFFFu);      \
            float _x = (basep)[_idx];                                  \
            float _y = (basep)[NPTS + _idx];                           \
            float _z = (basep)[2 * NPTS + _idx];                       \
            _sx += _x; _sy += _y; _sz += _z;                           \
            _sxx = fmaf(_x, _x, _sxx); _sxy = fmaf(_x, _y, _sxy); _sxz = fmaf(_x, _z, _sxz); \
            _syy = fmaf(_y, _y, _syy); _syz = fmaf(_y, _z, _syz); _szz = fmaf(_z, _z, _szz); \
        }                                                              \
        const float _iK = 1.0f / KNN;                                  \
        float _mx = _sx * _iK, _my = _sy * _iK, _mz = _sz * _iK;       \
        smallest_eigvec(_sxx * _iK - _mx * _mx, _sxy * _iK - _mx * _my, \
                        _sxz * _iK - _mx * _mz, _syy * _iK - _my * _my, \
                        _syz * _iK - _my * _mz, _szz * _iK - _mz * _mz, \
                        vx, vy, vz);                                   \
    } while (0)

__global__ void zero_out_kernel(float* __restrict__ out) {
    if (threadIdx.x == 0) out[0] = 0.0f;
}

// One block = 128 points of one batch, BOTH clouds. 16 waves (TPB=1024) give
// 4 waves/SIMD at 1 block/CU; lane l owns points (base+l, base+l+64); wave w
// scans segment w of the full 64 KiB staged cloud. Loss in-block, 1 atomicAdd.
__global__ __launch_bounds__(TPB, 4) void knn_normal_loss(
    const float* __restrict__ pred, const float* __restrict__ gt,
    float* __restrict__ out) {
    __shared__ float4 pts[NPTS + 8];   // 64 KiB + prefetch pad; aliased as keybuf

    const int b = blockIdx.y;
    const float* __restrict__ baseP = pred + b * 3 * NPTS;
    const float* __restrict__ baseG = gt + b * 3 * NPTS;
    const int tid = threadIdx.x;
    const int lane = tid & 63;
    const int w = tid >> 6;           // wave id = segment id (0..15)
    const int s0 = w * SEGC;          // wave-uniform segment offset
    float* keybuf = (float*)pts;

    const int pt0 = blockIdx.x * QPB + lane;
    const int pt1 = pt0 + 64;

    float kP0[KNN], kP1[KNN];         // pred top-10 (final in wave 0)
    float kG0[KNN], kG1[KNN];         // gt   top-10 (final in wave 0)

    SCAN_CLOUD(baseP, kP0, kP1);
    SCAN_CLOUD(baseG, kG0, kG1);

    if (w == 0) {
        float acc;
        {
            float pvx, pvy, pvz, gvx, gvy, gvz;
            COMPUTE_NORMAL(kP0, baseP, pvx, pvy, pvz);
            COMPUTE_NORMAL(kG0, baseG, gvx, gvy, gvz);
            float dot = pvx * gvx + pvy * gvy + pvz * gvz;
            float npn = sqrtf(pvx * pvx + pvy * pvy + pvz * pvz);
            float ngn = sqrtf(gvx * gvx + gvy * gvy + gvz * gvz);
            acc = 1.0f - fabsf(dot / fmaxf(npn * ngn, 1e-8f));
        }
        {
            float pvx, pvy, pvz, gvx, gvy, gvz;
            COMPUTE_NORMAL(kP1, baseP, pvx, pvy, pvz);
            COMPUTE_NORMAL(kG1, baseG, gvx, gvy, gvz);
            float dot = pvx * gvx + pvy * gvy + pvz * gvz;
            float npn = sqrtf(pvx * pvx + pvy * pvy + pvz * pvz);
            float ngn = sqrtf(gvx * gvx + gvy * gvy + gvz * gvz);
            acc += 1.0f - fabsf(dot / fmaxf(npn * ngn, 1e-8f));
        }
        // wave reduction, then one atomic per block
        for (int off = 32; off > 0; off >>= 1) acc += __shfl_down(acc, off);
        if (lane == 0) atomicAdd(out, acc * (1.0f / (float)BN));
    }
}

extern "C" void kernel_launch(void* const* d_in, const int* in_sizes, int n_in,
                              void* d_out, int out_size, void* d_ws, size_t ws_size,
                              hipStream_t stream) {
    const float* pred = (const float*)d_in[0];
    const float* gt = (const float*)d_in[1];
    float* out = (float*)d_out;

    zero_out_kernel<<<1, 64, 0, stream>>>(out);
    dim3 grid(GRIDX, BATCH);          // 32 x 8 = 256 blocks (1 per CU)
    knn_normal_loss<<<grid, TPB, 0, stream>>>(pred, gt, out);
}